// Round 1
// baseline (44.725 us; speedup 1.0000x reference)
//
#include <hip/hip_runtime.h>

// ---------------------------------------------------------------------------
// QuantumEncoder: co = tanh(x@W1.T+b1); angles = co[:, :4];
// qf = 4-qubit circuit expectation <Z_q>; mu/logvar = qf @ W.T + b.
//
// Key algebraic reduction: batched part of the circuit is RY(angles_q)|0>
// per qubit -> REAL product state s[16]. The rest (theta-parameterized
// layers + CNOTs) is a fixed 16x16 unitary V. qf_i = s^T M_i s with
// M_i = Re(V^dag diag(sign_i) V): four real symmetric 16x16 matrices,
// precomputed once per launch into d_ws by a tiny setup kernel.
// ---------------------------------------------------------------------------

__global__ void precompute_M_kernel(const float* __restrict__ theta,
                                    float* __restrict__ M) {
  __shared__ float Vre[16][16];  // V[z][k]: column k = circuit applied to e_k
  __shared__ float Vim[16][16];
  int t = threadIdx.x;
  if (t < 16) {
    float re[16], im[16];
#pragma unroll
    for (int z = 0; z < 16; ++z) { re[z] = 0.f; im[z] = 0.f; }
    re[t] = 1.f;
    for (int layer = 0; layer < 2; ++layer) {
#pragma unroll
      for (int q = 0; q < 4; ++q) {
        float th = theta[layer * 4 + q];
        float c, s;
        sincosf(0.5f * th, &s, &c);
        // Rx(th) = [[c, -i s], [-i s, c]]
#pragma unroll
        for (int z = 0; z < 16; ++z) {
          if (!((z >> q) & 1)) {
            int z1 = z | (1 << q);
            float ar = re[z], ai = im[z], br = re[z1], bi = im[z1];
            re[z]  = c * ar + s * bi;  im[z]  = c * ai - s * br;
            re[z1] = c * br + s * ai;  im[z1] = c * bi - s * ar;
          }
        }
        // Ry(th) = [[c, -s], [s, c]]
#pragma unroll
        for (int z = 0; z < 16; ++z) {
          if (!((z >> q) & 1)) {
            int z1 = z | (1 << q);
            float ar = re[z], ai = im[z], br = re[z1], bi = im[z1];
            re[z]  = c * ar - s * br;  im[z]  = c * ai - s * bi;
            re[z1] = s * ar + c * br;  im[z1] = s * ai + c * bi;
          }
        }
        // Rz(th) = diag(e^{-i th/2}, e^{+i th/2})
#pragma unroll
        for (int z = 0; z < 16; ++z) {
          if (!((z >> q) & 1)) {
            int z1 = z | (1 << q);
            float ar = re[z], ai = im[z], br = re[z1], bi = im[z1];
            re[z]  = c * ar + s * ai;  im[z]  = c * ai - s * ar;
            re[z1] = c * br - s * bi;  im[z1] = c * bi + s * br;
          }
        }
      }
      // CNOT ring: (c,t) = (0,1),(1,2),(2,3),(3,0). bit c set -> flip bit t.
      const int cqs[4] = {0, 1, 2, 3};
      const int tqs[4] = {1, 2, 3, 0};
#pragma unroll
      for (int g = 0; g < 4; ++g) {
#pragma unroll
        for (int z = 0; z < 16; ++z) {
          if (((z >> cqs[g]) & 1) && !((z >> tqs[g]) & 1)) {
            int z1 = z | (1 << tqs[g]);
            float tr = re[z], ti = im[z];
            re[z] = re[z1];  im[z] = im[z1];
            re[z1] = tr;     im[z1] = ti;
          }
        }
      }
    }
#pragma unroll
    for (int z = 0; z < 16; ++z) { Vre[z][t] = re[z]; Vim[z][t] = im[z]; }
  }
  __syncthreads();
  // M_i[a][b] = sum_z sign_i(z) * Re(V[z,a] * conj(V[z,b]))
  // sign_i(z) = +1 if bit (3-i) of z is 0 else -1  (qf[:,i] = <Z_{3-i}>)
  int i = t >> 4, a = t & 15;
#pragma unroll
  for (int b = 0; b < 16; ++b) {
    float acc = 0.f;
#pragma unroll
    for (int z = 0; z < 16; ++z) {
      float sg = ((z >> (3 - i)) & 1) ? -1.f : 1.f;
      acc += sg * (Vre[z][a] * Vre[z][b] + Vim[z][a] * Vim[z][b]);
    }
    M[i * 256 + a * 16 + b] = acc;
  }
}

#define D_IN 1024

__global__ __launch_bounds__(256) void fused_qenc_kernel(
    const float* __restrict__ x, const float* __restrict__ W1,
    const float* __restrict__ b1, const float* __restrict__ M,
    const float* __restrict__ Wmu, const float* __restrict__ bmu,
    const float* __restrict__ Wlv, const float* __restrict__ blv,
    float* __restrict__ out, int B) {
  const int lane = threadIdx.x & 63;
  const int wave = blockIdx.x * (blockDim.x >> 6) + (threadIdx.x >> 6);
  const int nwaves = gridDim.x * (blockDim.x >> 6);

  // --- loop-invariant per-lane register loads ---
  // W1 fragments: lane covers columns [k*256 + lane*4, +4) of rows 0..3
  float4 w1f[4][4];
#pragma unroll
  for (int j = 0; j < 4; ++j)
#pragma unroll
    for (int k = 0; k < 4; ++k)
      w1f[j][k] = *reinterpret_cast<const float4*>(W1 + j * D_IN + k * 256 + lane * 4);
  float b1r[4];
#pragma unroll
  for (int j = 0; j < 4; ++j) b1r[j] = b1[j];

  const int mi = lane >> 4;   // which feature i this lane serves
  const int mz = lane & 15;   // which row a of M_i this lane serves
  float Mr[16];
  {
    const float4* mp = reinterpret_cast<const float4*>(M + mi * 256 + mz * 16);
#pragma unroll
    for (int k = 0; k < 4; ++k) {
      float4 v = mp[k];
      Mr[4 * k + 0] = v.x; Mr[4 * k + 1] = v.y; Mr[4 * k + 2] = v.z; Mr[4 * k + 3] = v.w;
    }
  }
  float wmu[4], wlv[4];
#pragma unroll
  for (int j = 0; j < 4; ++j) { wmu[j] = Wmu[lane * 4 + j]; wlv[j] = Wlv[lane * 4 + j]; }
  const float bmur = bmu[lane], blvr = blv[lane];

  const size_t mu_base = 0;
  const size_t lv_base = (size_t)B * 64;

  for (int r = wave; r < B; r += nwaves) {
    const float* xr = x + (size_t)r * D_IN;
    float4 xv[4];
#pragma unroll
    for (int k = 0; k < 4; ++k)
      xv[k] = *reinterpret_cast<const float4*>(xr + k * 256 + lane * 4);

    // 4 dot products (x row vs W1 rows 0..3), per-lane partial then butterfly
    float acc[4];
#pragma unroll
    for (int j = 0; j < 4; ++j) {
      float a = 0.f;
#pragma unroll
      for (int k = 0; k < 4; ++k) {
        a += xv[k].x * w1f[j][k].x + xv[k].y * w1f[j][k].y +
             xv[k].z * w1f[j][k].z + xv[k].w * w1f[j][k].w;
      }
      acc[j] = a;
    }
#pragma unroll
    for (int j = 0; j < 4; ++j) {
      float a = acc[j];
#pragma unroll
      for (int off = 32; off; off >>= 1) a += __shfl_xor(a, off);
      acc[j] = a;
    }

    // angles -> per-qubit (cos, sin) of half-angle
    float cq[4], sq[4];
#pragma unroll
    for (int j = 0; j < 4; ++j) {
      float ang = tanhf(acc[j] + b1r[j]);
      sincosf(0.5f * ang, &sq[j], &cq[j]);
    }

    // real product state s[16]
    float sv[16];
#pragma unroll
    for (int z = 0; z < 16; ++z) {
      float v = ((z & 1) ? sq[0] : cq[0]);
      v *= (((z >> 1) & 1) ? sq[1] : cq[1]);
      v *= (((z >> 2) & 1) ? sq[2] : cq[2]);
      v *= (((z >> 3) & 1) ? sq[3] : cq[3]);
      sv[z] = v;
    }

    // qf_i = sum_a sv[a] * sum_b M_i[a][b] sv[b]; lane handles (i=mi, a=mz)
    float tdot = 0.f;
#pragma unroll
    for (int k = 0; k < 16; ++k) tdot += Mr[k] * sv[k];
    // sv[mz] without runtime register indexing (rule #20):
    float svm = ((mz & 1) ? sq[0] : cq[0]);
    svm *= (((mz >> 1) & 1) ? sq[1] : cq[1]);
    svm *= (((mz >> 2) & 1) ? sq[2] : cq[2]);
    svm *= (((mz >> 3) & 1) ? sq[3] : cq[3]);
    float p = tdot * svm;
#pragma unroll
    for (int off = 8; off; off >>= 1) p += __shfl_xor(p, off);

    float qf[4];
#pragma unroll
    for (int i = 0; i < 4; ++i) qf[i] = __shfl(p, i * 16);

    // per-lane outputs: mu[lane], logvar[lane]
    float mu = bmur, lv = blvr;
#pragma unroll
    for (int j = 0; j < 4; ++j) { mu += qf[j] * wmu[j]; lv += qf[j] * wlv[j]; }
    out[mu_base + (size_t)r * 64 + lane] = mu;
    out[lv_base + (size_t)r * 64 + lane] = lv;
  }
}

extern "C" void kernel_launch(void* const* d_in, const int* in_sizes, int n_in,
                              void* d_out, int out_size, void* d_ws, size_t ws_size,
                              hipStream_t stream) {
  const float* x   = (const float*)d_in[0];
  const float* W1  = (const float*)d_in[1];
  const float* b1  = (const float*)d_in[2];
  const float* qp  = (const float*)d_in[3];
  const float* Wmu = (const float*)d_in[4];
  const float* bmu = (const float*)d_in[5];
  const float* Wlv = (const float*)d_in[6];
  const float* blv = (const float*)d_in[7];
  float* out = (float*)d_out;
  float* M = (float*)d_ws;  // 4 * 16 * 16 floats = 4 KiB

  const int B = out_size / 128;  // out = mu(B,64) ++ logvar(B,64)

  precompute_M_kernel<<<1, 64, 0, stream>>>(qp, M);

  int blocks = 2048;
  int waves_needed = B;  // one wave per row
  int max_blocks = (waves_needed + 3) / 4;
  if (blocks > max_blocks) blocks = max_blocks;
  fused_qenc_kernel<<<blocks, 256, 0, stream>>>(x, W1, b1, M, Wmu, bmu, Wlv, blv,
                                                out, B);
}

// Round 2
// 44.211 us; speedup vs baseline: 1.0116x; 1.0116x over previous
//
#include <hip/hip_runtime.h>

typedef float f32x4 __attribute__((ext_vector_type(4)));

#define D_IN 1024

// tanh(x) = 1 - 2/(exp(2x)+1): v_exp + v_rcp, robust for all x (inf-safe)
__device__ __forceinline__ float fast_tanh(float x) {
  float e = __expf(2.0f * x);
  return 1.0f - 2.0f * __builtin_amdgcn_rcpf(e + 1.0f);
}

// ---------------------------------------------------------------------------
// Single fused kernel. Per-block prologue builds M_i = Re(V^dag D_i V) in LDS
// (V = fixed 16x16 unitary from quantum_params), then the grid-stride main
// loop does: angles = tanh(x_row . W1[0:4]) -> product state (rank-1 A/B
// factors) -> qf_i = s^T M_i s -> mu/logvar.
// ---------------------------------------------------------------------------
__global__ __launch_bounds__(256) void fused_qenc_kernel(
    const float* __restrict__ x, const float* __restrict__ W1,
    const float* __restrict__ b1, const float* __restrict__ theta,
    const float* __restrict__ Wmu, const float* __restrict__ bmu,
    const float* __restrict__ Wlv, const float* __restrict__ blv,
    float* __restrict__ out, int B) {
  __shared__ float Vre[16][17];
  __shared__ float Vim[16][17];
  __shared__ float Mlds[4][16][16];

  const int tid = threadIdx.x;

  // ---- prologue A: evolve V on threads 0..15 (column t) ----
  if (tid < 16) {
    float re[16], im[16];
#pragma unroll
    for (int z = 0; z < 16; ++z) { re[z] = 0.f; im[z] = 0.f; }
    re[tid] = 1.f;
    for (int layer = 0; layer < 2; ++layer) {
#pragma unroll
      for (int q = 0; q < 4; ++q) {
        float th = theta[layer * 4 + q];
        float s, c;
        __sincosf(0.5f * th, &s, &c);
        // Rx
#pragma unroll
        for (int z = 0; z < 16; ++z) {
          if (!((z >> q) & 1)) {
            int z1 = z | (1 << q);
            float ar = re[z], ai = im[z], br = re[z1], bi = im[z1];
            re[z]  = c * ar + s * bi;  im[z]  = c * ai - s * br;
            re[z1] = c * br + s * ai;  im[z1] = c * bi - s * ar;
          }
        }
        // Ry
#pragma unroll
        for (int z = 0; z < 16; ++z) {
          if (!((z >> q) & 1)) {
            int z1 = z | (1 << q);
            float ar = re[z], ai = im[z], br = re[z1], bi = im[z1];
            re[z]  = c * ar - s * br;  im[z]  = c * ai - s * bi;
            re[z1] = s * ar + c * br;  im[z1] = s * ai + c * bi;
          }
        }
        // Rz
#pragma unroll
        for (int z = 0; z < 16; ++z) {
          if (!((z >> q) & 1)) {
            int z1 = z | (1 << q);
            float ar = re[z], ai = im[z], br = re[z1], bi = im[z1];
            re[z]  = c * ar + s * ai;  im[z]  = c * ai - s * ar;
            re[z1] = c * br - s * bi;  im[z1] = c * bi + s * br;
          }
        }
      }
      // CNOT ring (0,1)(1,2)(2,3)(3,0)
      const int cqs[4] = {0, 1, 2, 3};
      const int tqs[4] = {1, 2, 3, 0};
#pragma unroll
      for (int gIdx = 0; gIdx < 4; ++gIdx) {
#pragma unroll
        for (int z = 0; z < 16; ++z) {
          if (((z >> cqs[gIdx]) & 1) && !((z >> tqs[gIdx]) & 1)) {
            int z1 = z | (1 << tqs[gIdx]);
            float tr = re[z], ti = im[z];
            re[z] = re[z1];  im[z] = im[z1];
            re[z1] = tr;     im[z1] = ti;
          }
        }
      }
    }
#pragma unroll
    for (int z = 0; z < 16; ++z) { Vre[z][tid] = re[z]; Vim[z][tid] = im[z]; }
  }
  __syncthreads();

  // ---- prologue B: M formation, 256 threads x 4 entries each ----
  {
    const int i = tid >> 6, a = (tid >> 2) & 15, b0 = (tid & 3) * 4;
    float ra[16], ia[16];
#pragma unroll
    for (int z = 0; z < 16; ++z) { ra[z] = Vre[z][a]; ia[z] = Vim[z][a]; }
#pragma unroll
    for (int k = 0; k < 4; ++k) {
      const int b = b0 + k;
      float acc = 0.f;
#pragma unroll
      for (int z = 0; z < 16; ++z) {
        float sg = ((z >> (3 - i)) & 1) ? -1.f : 1.f;
        acc += sg * (ra[z] * Vre[z][b] + ia[z] * Vim[z][b]);
      }
      Mlds[i][a][b] = acc;
    }
  }
  __syncthreads();

  // ---- main-loop invariants ----
  const int lane = tid & 63;
  const int wave = blockIdx.x * 4 + (tid >> 6);
  const int nwaves = gridDim.x * 4;
  const int g = lane >> 4;    // feature index this lane reduces
  const int mz = lane & 15;   // M row this lane owns

  f32x4 w1f[4][4];
#pragma unroll
  for (int j = 0; j < 4; ++j)
#pragma unroll
    for (int k = 0; k < 4; ++k)
      w1f[j][k] = *reinterpret_cast<const f32x4*>(W1 + j * D_IN + k * 256 + lane * 4);
  float b1r[4];
#pragma unroll
  for (int j = 0; j < 4; ++j) b1r[j] = b1[j];

  float Mr[16];
#pragma unroll
  for (int k = 0; k < 16; ++k) Mr[k] = Mlds[g][mz][k];

  float wmuP[4], wlvP[4];
#pragma unroll
  for (int k = 0; k < 4; ++k) {
    wmuP[k] = Wmu[lane * 4 + (g ^ k)];
    wlvP[k] = Wlv[lane * 4 + (g ^ k)];
  }
  const float bmur = bmu[lane], blvr = blv[lane];
  const size_t lv_base = (size_t)B * 64;

  int r = wave;
  if (r >= B) return;

  f32x4 xv[4];
  {
    const f32x4* xp = reinterpret_cast<const f32x4*>(x + (size_t)r * D_IN);
#pragma unroll
    for (int k = 0; k < 4; ++k) xv[k] = __builtin_nontemporal_load(xp + k * 64 + lane);
  }

  while (true) {
    // ---- dot partials (last use of xv) ----
    float acc[4];
#pragma unroll
    for (int j = 0; j < 4; ++j) {
      float a = 0.f;
#pragma unroll
      for (int k = 0; k < 4; ++k) {
        a = fmaf(xv[k].x, w1f[j][k].x, a);
        a = fmaf(xv[k].y, w1f[j][k].y, a);
        a = fmaf(xv[k].z, w1f[j][k].z, a);
        a = fmaf(xv[k].w, w1f[j][k].w, a);
      }
      acc[j] = a;
    }

    // ---- prefetch next row into the same regs (hides HBM under the tail) ----
    const int rn = r + nwaves;
    if (rn < B) {
      const f32x4* xp = reinterpret_cast<const f32x4*>(x + (size_t)rn * D_IN);
#pragma unroll
      for (int k = 0; k < 4; ++k) xv[k] = __builtin_nontemporal_load(xp + k * 64 + lane);
    }

    // ---- 64-lane butterfly reduce, all 4 dots (canonical order) ----
#pragma unroll
    for (int j = 0; j < 4; ++j) {
      float a = acc[j];
#pragma unroll
      for (int off = 32; off; off >>= 1) a += __shfl_xor(a, off);
      acc[j] = a;
    }

    // ---- angles -> half-angle (cos, sin) ----
    float cq[4], sq[4];
#pragma unroll
    for (int j = 0; j < 4; ++j) {
      float ang = fast_tanh(acc[j] + b1r[j]);
      __sincosf(0.5f * ang, &sq[j], &cq[j]);
    }

    // rank-1 factors of the product state: sv[z] = A[z&3] * Bf[z>>2]
    const float A0 = cq[0] * cq[1], A1 = sq[0] * cq[1];
    const float A2 = cq[0] * sq[1], A3 = sq[0] * sq[1];
    const float B0 = cq[2] * cq[3], B1 = sq[2] * cq[3];
    const float B2 = cq[2] * sq[3], B3 = sq[2] * sq[3];

    // tdot = M_g[mz][:] . sv
    float t0 = fmaf(Mr[3], A3, fmaf(Mr[2], A2, fmaf(Mr[1], A1, Mr[0] * A0)));
    float t1 = fmaf(Mr[7], A3, fmaf(Mr[6], A2, fmaf(Mr[5], A1, Mr[4] * A0)));
    float t2 = fmaf(Mr[11], A3, fmaf(Mr[10], A2, fmaf(Mr[9], A1, Mr[8] * A0)));
    float t3 = fmaf(Mr[15], A3, fmaf(Mr[14], A2, fmaf(Mr[13], A1, Mr[12] * A0)));
    float tdot = fmaf(t3, B3, fmaf(t2, B2, fmaf(t1, B1, t0 * B0)));

    // sv[mz] via per-bit selects (no runtime register indexing)
    float svm = ((mz & 1) ? sq[0] : cq[0]);
    svm *= ((mz & 2) ? sq[1] : cq[1]);
    svm *= ((mz & 4) ? sq[2] : cq[2]);
    svm *= ((mz & 8) ? sq[3] : cq[3]);

    float p = tdot * svm;
#pragma unroll
    for (int off = 8; off; off >>= 1) p += __shfl_xor(p, off);
    // p = qf_g in every lane of group g; exchange across groups
    float v1 = __shfl_xor(p, 16);   // qf_{g^1}
    float v2 = __shfl_xor(p, 32);   // qf_{g^2}
    float v3 = __shfl_xor(v1, 32);  // qf_{g^3}

    float mu = fmaf(v3, wmuP[3], fmaf(v2, wmuP[2], fmaf(v1, wmuP[1], fmaf(p, wmuP[0], bmur))));
    float lv = fmaf(v3, wlvP[3], fmaf(v2, wlvP[2], fmaf(v1, wlvP[1], fmaf(p, wlvP[0], blvr))));
    __builtin_nontemporal_store(mu, out + (size_t)r * 64 + lane);
    __builtin_nontemporal_store(lv, out + lv_base + (size_t)r * 64 + lane);

    if (rn >= B) break;
    r = rn;
  }
}

extern "C" void kernel_launch(void* const* d_in, const int* in_sizes, int n_in,
                              void* d_out, int out_size, void* d_ws, size_t ws_size,
                              hipStream_t stream) {
  const float* x   = (const float*)d_in[0];
  const float* W1  = (const float*)d_in[1];
  const float* b1  = (const float*)d_in[2];
  const float* qp  = (const float*)d_in[3];
  const float* Wmu = (const float*)d_in[4];
  const float* bmu = (const float*)d_in[5];
  const float* Wlv = (const float*)d_in[6];
  const float* blv = (const float*)d_in[7];
  float* out = (float*)d_out;

  const int B = out_size / 128;  // out = mu(B,64) ++ logvar(B,64)

  int blocks = (B + 31) / 32;    // 4 waves/block, ~8 rows/wave at B=32768
  if (blocks > 1024) blocks = 1024;
  fused_qenc_kernel<<<blocks, 256, 0, stream>>>(x, W1, b1, qp, Wmu, bmu, Wlv, blv,
                                                out, B);
}

// Round 6
// 44.117 us; speedup vs baseline: 1.0138x; 1.0021x over previous
//
#include <hip/hip_runtime.h>

typedef float f32x4 __attribute__((ext_vector_type(4)));

#define D_IN 1024

// tanh(x) = 1 - 2/(exp(2x)+1): v_exp + v_rcp, robust for all x
__device__ __forceinline__ float fast_tanh(float x) {
  float e = __expf(2.0f * x);
  return 1.0f - 2.0f * __builtin_amdgcn_rcpf(e + 1.0f);
}

// ---------------------------------------------------------------------------
// Single fused kernel, low-VGPR variant (target <=128 -> 4 waves/SIMD).
// W1 fragments live in LDS (not registers). Prologue per block: stage W1,
// evolve V (16x16 unitary from theta), form M_i = Re(V^dag D_i V) in LDS.
// Main grid-stride loop: wave-per-row dots -> fused butterfly -> tanh/sincos
// -> rank-1 product state -> qf_i = s^T M_i s -> mu/logvar.
// ---------------------------------------------------------------------------
__global__ __launch_bounds__(256, 4) void fused_qenc_kernel(
    const float* __restrict__ x, const float* __restrict__ W1,
    const float* __restrict__ b1, const float* __restrict__ theta,
    const float* __restrict__ Wmu, const float* __restrict__ bmu,
    const float* __restrict__ Wlv, const float* __restrict__ blv,
    float* __restrict__ out, int B) {
  __shared__ float Vre[16][17];
  __shared__ float Vim[16][17];
  __shared__ float Mlds[4][16][16];
  __shared__ f32x4 W1L[1024];  // [j][k*64 + lane] as float4: j*256 + k*64 + l

  const int tid = threadIdx.x;

  // ---- prologue: stage W1 rows 0..3 into LDS (all 256 threads) ----
  {
    const f32x4* wp = reinterpret_cast<const f32x4*>(W1);
#pragma unroll
    for (int k = 0; k < 4; ++k) W1L[k * 256 + tid] = wp[k * 256 + tid];
  }

  // ---- prologue: evolve V on threads 0..15 (column t) ----
  if (tid < 16) {
    float re[16], im[16];
#pragma unroll
    for (int z = 0; z < 16; ++z) { re[z] = 0.f; im[z] = 0.f; }
    re[tid] = 1.f;
    for (int layer = 0; layer < 2; ++layer) {
#pragma unroll
      for (int q = 0; q < 4; ++q) {
        float th = theta[layer * 4 + q];
        float s, c;
        __sincosf(0.5f * th, &s, &c);
        // Rx
#pragma unroll
        for (int z = 0; z < 16; ++z) {
          if (!((z >> q) & 1)) {
            int z1 = z | (1 << q);
            float ar = re[z], ai = im[z], br = re[z1], bi = im[z1];
            re[z]  = c * ar + s * bi;  im[z]  = c * ai - s * br;
            re[z1] = c * br + s * ai;  im[z1] = c * bi - s * ar;
          }
        }
        // Ry
#pragma unroll
        for (int z = 0; z < 16; ++z) {
          if (!((z >> q) & 1)) {
            int z1 = z | (1 << q);
            float ar = re[z], ai = im[z], br = re[z1], bi = im[z1];
            re[z]  = c * ar - s * br;  im[z]  = c * ai - s * bi;
            re[z1] = s * ar + c * br;  im[z1] = s * ai + c * bi;
          }
        }
        // Rz
#pragma unroll
        for (int z = 0; z < 16; ++z) {
          if (!((z >> q) & 1)) {
            int z1 = z | (1 << q);
            float ar = re[z], ai = im[z], br = re[z1], bi = im[z1];
            re[z]  = c * ar + s * ai;  im[z]  = c * ai - s * ar;
            re[z1] = c * br - s * bi;  im[z1] = c * bi + s * br;
          }
        }
      }
      // CNOT ring (0,1)(1,2)(2,3)(3,0)
      const int cqs[4] = {0, 1, 2, 3};
      const int tqs[4] = {1, 2, 3, 0};
#pragma unroll
      for (int gIdx = 0; gIdx < 4; ++gIdx) {
#pragma unroll
        for (int z = 0; z < 16; ++z) {
          if (((z >> cqs[gIdx]) & 1) && !((z >> tqs[gIdx]) & 1)) {
            int z1 = z | (1 << tqs[gIdx]);
            float tr = re[z], ti = im[z];
            re[z] = re[z1];  im[z] = im[z1];
            re[z1] = tr;     im[z1] = ti;
          }
        }
      }
    }
#pragma unroll
    for (int z = 0; z < 16; ++z) { Vre[z][tid] = re[z]; Vim[z][tid] = im[z]; }
  }
  __syncthreads();

  // ---- prologue: M formation, 256 threads x 4 entries each ----
  {
    const int i = tid >> 6, a = (tid >> 2) & 15, b0 = (tid & 3) * 4;
    float ra[16], ia[16];
#pragma unroll
    for (int z = 0; z < 16; ++z) { ra[z] = Vre[z][a]; ia[z] = Vim[z][a]; }
#pragma unroll
    for (int k = 0; k < 4; ++k) {
      const int b = b0 + k;
      float acc = 0.f;
#pragma unroll
      for (int z = 0; z < 16; ++z) {
        float sg = ((z >> (3 - i)) & 1) ? -1.f : 1.f;
        acc += sg * (ra[z] * Vre[z][b] + ia[z] * Vim[z][b]);
      }
      Mlds[i][a][b] = acc;
    }
  }
  __syncthreads();

  // ---- main-loop invariants ----
  const int lane = tid & 63;
  const int wave = blockIdx.x * 4 + (tid >> 6);
  const int nwaves = gridDim.x * 4;
  const int g = lane >> 4;    // feature this lane's 16-group reduces
  const int mz = lane & 15;   // M row this lane owns
  const bool bit4 = (lane & 16) != 0;
  const bool bit5 = (lane & 32) != 0;

  float Mr[16];
#pragma unroll
  for (int k = 0; k < 16; ++k) Mr[k] = Mlds[g][mz][k];

  float b1r[4];
#pragma unroll
  for (int j = 0; j < 4; ++j) b1r[j] = b1[j];

  float wmuP[4], wlvP[4];
#pragma unroll
  for (int k = 0; k < 4; ++k) {
    wmuP[k] = Wmu[lane * 4 + (g ^ k)];
    wlvP[k] = Wlv[lane * 4 + (g ^ k)];
  }
  const float bmur = bmu[lane], blvr = blv[lane];
  const size_t lv_base = (size_t)B * 64;

  int r = wave;
  if (r >= B) return;

  f32x4 xv[4];
  {
    const f32x4* xp = reinterpret_cast<const f32x4*>(x + (size_t)r * D_IN);
#pragma unroll
    for (int k = 0; k < 4; ++k) xv[k] = __builtin_nontemporal_load(xp + k * 64 + lane);
  }

  while (true) {
    // ---- dot partials: W1 frags from LDS, x from regs (last use of xv) ----
    float acc[4] = {0.f, 0.f, 0.f, 0.f};
#pragma unroll
    for (int k = 0; k < 4; ++k) {
      f32x4 xk = xv[k];
#pragma unroll
      for (int j = 0; j < 4; ++j) {
        f32x4 w = W1L[j * 256 + k * 64 + lane];
        acc[j] = fmaf(xk.x, w.x, acc[j]);
        acc[j] = fmaf(xk.y, w.y, acc[j]);
        acc[j] = fmaf(xk.z, w.z, acc[j]);
        acc[j] = fmaf(xk.w, w.w, acc[j]);
      }
    }

    // ---- prefetch next row into the same regs ----
    const int rn = r + nwaves;
    if (rn < B) {
      const f32x4* xp = reinterpret_cast<const f32x4*>(x + (size_t)rn * D_IN);
#pragma unroll
      for (int k = 0; k < 4; ++k) xv[k] = __builtin_nontemporal_load(xp + k * 64 + lane);
    }

    // ---- fused butterfly: 7 shfls reduce all 4 dots ----
    // After C-steps lane holds dot_f, f = 2*bit4 + bit5.
    float u = bit5 ? acc[1] : acc[0];
    u += __shfl_xor(bit5 ? acc[0] : acc[1], 32);
    float v = bit5 ? acc[3] : acc[2];
    v += __shfl_xor(bit5 ? acc[2] : acc[3], 32);
    float w = bit4 ? v : u;
    w += __shfl_xor(bit4 ? u : v, 16);
#pragma unroll
    for (int off = 8; off; off >>= 1) w += __shfl_xor(w, off);
    // redistribute: every lane needs all four dots
    float vA = __shfl_xor(w, 16);  // dot_{f^2}
    float vB = __shfl_xor(w, 32);  // dot_{f^1}
    float vC = __shfl_xor(w, 48);  // dot_{f^3}
    float d0 = bit4 ? (bit5 ? vC : vA) : (bit5 ? vB : w);
    float d1 = bit4 ? (bit5 ? vA : vC) : (bit5 ? w : vB);
    float d2 = bit4 ? (bit5 ? vB : w) : (bit5 ? vC : vA);
    float d3 = bit4 ? (bit5 ? w : vB) : (bit5 ? vA : vC);

    // ---- angles -> half-angle (cos, sin) ----
    float cq[4], sq[4];
    __sincosf(0.5f * fast_tanh(d0 + b1r[0]), &sq[0], &cq[0]);
    __sincosf(0.5f * fast_tanh(d1 + b1r[1]), &sq[1], &cq[1]);
    __sincosf(0.5f * fast_tanh(d2 + b1r[2]), &sq[2], &cq[2]);
    __sincosf(0.5f * fast_tanh(d3 + b1r[3]), &sq[3], &cq[3]);

    // rank-1 factors of the product state: sv[z] = A[z&3] * Bf[z>>2]
    const float A0 = cq[0] * cq[1], A1 = sq[0] * cq[1];
    const float A2 = cq[0] * sq[1], A3 = sq[0] * sq[1];
    const float B0 = cq[2] * cq[3], B1 = sq[2] * cq[3];
    const float B2 = cq[2] * sq[3], B3 = sq[2] * sq[3];

    // tdot = M_g[mz][:] . sv
    float t0 = fmaf(Mr[3], A3, fmaf(Mr[2], A2, fmaf(Mr[1], A1, Mr[0] * A0)));
    float t1 = fmaf(Mr[7], A3, fmaf(Mr[6], A2, fmaf(Mr[5], A1, Mr[4] * A0)));
    float t2 = fmaf(Mr[11], A3, fmaf(Mr[10], A2, fmaf(Mr[9], A1, Mr[8] * A0)));
    float t3 = fmaf(Mr[15], A3, fmaf(Mr[14], A2, fmaf(Mr[13], A1, Mr[12] * A0)));
    float tdot = fmaf(t3, B3, fmaf(t2, B2, fmaf(t1, B1, t0 * B0)));

    // sv[mz] via per-bit selects
    float svm = ((mz & 1) ? sq[0] : cq[0]);
    svm *= ((mz & 2) ? sq[1] : cq[1]);
    svm *= ((mz & 4) ? sq[2] : cq[2]);
    svm *= ((mz & 8) ? sq[3] : cq[3]);

    float p = tdot * svm;
#pragma unroll
    for (int off = 8; off; off >>= 1) p += __shfl_xor(p, off);
    // p = qf_g; exchange across 16-lane groups
    float v1 = __shfl_xor(p, 16);   // qf_{g^1}
    float v2 = __shfl_xor(p, 32);   // qf_{g^2}
    float v3 = __shfl_xor(v1, 32);  // qf_{g^3}

    float mu = fmaf(v3, wmuP[3], fmaf(v2, wmuP[2], fmaf(v1, wmuP[1], fmaf(p, wmuP[0], bmur))));
    float lv = fmaf(v3, wlvP[3], fmaf(v2, wlvP[2], fmaf(v1, wlvP[1], fmaf(p, wlvP[0], blvr))));
    __builtin_nontemporal_store(mu, out + (size_t)r * 64 + lane);
    __builtin_nontemporal_store(lv, out + lv_base + (size_t)r * 64 + lane);

    if (rn >= B) break;
    r = rn;
  }
}

extern "C" void kernel_launch(void* const* d_in, const int* in_sizes, int n_in,
                              void* d_out, int out_size, void* d_ws, size_t ws_size,
                              hipStream_t stream) {
  const float* x   = (const float*)d_in[0];
  const float* W1  = (const float*)d_in[1];
  const float* b1  = (const float*)d_in[2];
  const float* qp  = (const float*)d_in[3];
  const float* Wmu = (const float*)d_in[4];
  const float* bmu = (const float*)d_in[5];
  const float* Wlv = (const float*)d_in[6];
  const float* blv = (const float*)d_in[7];
  float* out = (float*)d_out;

  const int B = out_size / 128;  // out = mu(B,64) ++ logvar(B,64)

  int blocks = (B + 31) / 32;    // 4 waves/block, 8 rows/wave at B=32768
  if (blocks > 1024) blocks = 1024;
  fused_qenc_kernel<<<blocks, 256, 0, stream>>>(x, W1, b1, qp, Wmu, bmu, Wlv, blv,
                                                out, B);
}